// Round 12
// baseline (64.967 us; speedup 1.0000x reference)
//
#include <hip/hip_runtime.h>
#include <cstdint>
#include <cstddef>

// Problem constants (K=2048 tokens, D=128 feat, E=64 hidden)
#define KTOT 2048
#define DDIM 128
#define EDIM 64
#define RPB  4    // output rows per edge block
#define JR   512  // j-range per edge block (KTOT/4)
#define KPB  4    // z-rows per block in projection kernel

#define LOG2E 1.44269504088896f

typedef float v2f __attribute__((ext_vector_type(2)));

// ---------------------------------------------------------------------------
// Kernel A: per row k and unit e (log2-domain t = (z@W1+b)*log2e) computes
//   hiw = t_i*w2[e], Ei = 2^-t_i   (i-side)   hjw = t_j*w2[e], Ej = 2^-t_j
// written INTERLEAVED per (k, e-octet): tab[k][sub][16] =
//   { hw quad A (e=sub*8..+3), Ee quad A, hw quad B (e=sub*8+4..+7), Ee quad B }
// so the edge kernel marches ONE pointer with immediate offsets 0/16/32/48B.
// Edge loop algebra: silu-dot = sum_e (hiw+hjw)/(1 + Ei*Ej); b2 cancels.
// ---------------------------------------------------------------------------
__global__ void proj_kernel(const float* __restrict__ z,
                            const float* __restrict__ W1,
                            const float* __restrict__ b1,
                            const float* __restrict__ w2,
                            float* __restrict__ itab, float* __restrict__ jtab) {
  __shared__ float zrow[KPB][DDIM];
  const int t  = threadIdx.x;            // 0..127
  const int k0 = blockIdx.x * KPB;
#pragma unroll
  for (int r = 0; r < KPB; ++r) zrow[r][t] = z[(size_t)(k0 + r) * DDIM + t];
  __syncthreads();

  const int  e    = t & 63;
  const bool isHj = (t >= 64);           // wave-uniform (wave0 = i, wave1 = j)
  const float* Wcol = W1 + (isHj ? DDIM * EDIM : 0) + e;

  float acc[KPB];
  const float binit = isHj ? 0.0f : b1[e];
#pragma unroll
  for (int r = 0; r < KPB; ++r) acc[r] = binit;

#pragma unroll 4
  for (int d = 0; d < DDIM; ++d) {
    const float w = Wcol[(size_t)d * EDIM];   // coalesced 256B per wave
#pragma unroll
    for (int r = 0; r < KPB; ++r) acc[r] = fmaf(zrow[r][d], w, acc[r]);
  }

  const float wv = w2[e];
  float* tab = isHj ? jtab : itab;
  // interleaved slot: [k][sub][ (quad)*8 + c ] for hw, +4 for Ee
  const int sub = e >> 3, quad = (e >> 2) & 1, c = e & 3;
  const int slot = sub * 16 + quad * 8 + c;
#pragma unroll
  for (int r = 0; r < KPB; ++r) {
    const float tv = acc[r] * LOG2E;
    float* dst = tab + (size_t)(k0 + r) * 128 + slot;
    dst[0] = tv * wv;
    dst[4] = __builtin_amdgcn_exp2f(-tv);
  }
}

// ---------------------------------------------------------------------------
// Quad numerator/denominator (NO transcendentals):
//   u_k = hw_k + jw_k  (pk_add);  d_k = 1 + Ei_k*Ej_k  (pk_fma)
//   (Nq, Dq) s.t. sum_k u_k/d_k = Nq/Dq over the 4 elements.
// ---------------------------------------------------------------------------
__device__ __forceinline__ void quad_nd(const float4 hw, const float4 he,
                                        const float4 jw, const float4 je,
                                        float& Nq, float& Dq) {
  const v2f u01 = (v2f){hw.x, hw.y} + (v2f){jw.x, jw.y};
  const v2f u23 = (v2f){hw.z, hw.w} + (v2f){jw.z, jw.w};
  const v2f d01 = (v2f){he.x, he.y} * (v2f){je.x, je.y} + 1.0f;  // pk_fma
  const v2f d23 = (v2f){he.z, he.w} * (v2f){je.z, je.w} + 1.0f;
  const float n01 = fmaf(u01.x, d01.y, u01.y * d01.x);
  const float n23 = fmaf(u23.x, d23.y, u23.y * d23.x);
  const float p01 = d01.x * d01.y;
  const float p23 = d23.x * d23.y;
  Nq = fmaf(n01, p23, n23 * p01);
  Dq = p01 * p23;
}

// ---------------------------------------------------------------------------
// DPP butterfly sum over each aligned 8-lane group (no LDS pipe):
// xor1 = quad_perm[1,0,3,2] (0xB1); xor2 = quad_perm[2,3,0,1] (0x4E);
// then row_half_mirror (0x141): lane^7 supplies the other quad's sum.
// All 8 lanes end holding the full octet sum.
// ---------------------------------------------------------------------------
__device__ __forceinline__ float dpp_red8(float a) {
  int t;
  t = __builtin_amdgcn_update_dpp(0, __float_as_int(a), 0xB1, 0xF, 0xF, true);
  a += __int_as_float(t);
  t = __builtin_amdgcn_update_dpp(0, __float_as_int(a), 0x4E, 0xF, 0xF, true);
  a += __int_as_float(t);
  t = __builtin_amdgcn_update_dpp(0, __float_as_int(a), 0x141, 0xF, 0xF, true);
  a += __int_as_float(t);
  return a;
}

// ---------------------------------------------------------------------------
// Kernel B (phase 1): grid = 2048 blocks = (i-group 0..511) x (j-quarter 0..3).
// 256 threads (4 waves); __launch_bounds__(256,4) = cap 128, spill-proof.
// Lane layout: sub = lane&7 -> e-octet; jg = lane>>3 -> one of 8 j's/wave.
// 4 waves x 8 j = 32 j/iter -> 16 iters over JR=512 (unroll 2).
// Per iter per lane: ONE marching pointer, 4 loads at imm offsets 0/16/32/48B.
// Per row: 2 independent quad_nd chains + own rcp; DPP 3-add reduce.
// Epilogue (fused single pass): exp2 -> scalar global store + register sum.
// Phase 2 normalizes.
// ---------------------------------------------------------------------------
__global__ __launch_bounds__(256, 4) void edge_kernel(
    const float* __restrict__ itab, const float* __restrict__ jtab,
    float* __restrict__ out, float* __restrict__ partials) {
  __shared__ float logits[RPB][JR];      // 8 KB

  const int tid  = threadIdx.x;
  const int lane = tid & 63;
  const int wave = tid >> 6;             // 0..3
  const int sub  = lane & 7;             // e-octet index
  const int jg   = lane >> 3;            // 0..7
  const int ig   = blockIdx.x >> 2;      // i-group
  const int jq   = blockIdx.x & 3;       // j-quarter
  const int i0   = ig * RPB;

  // Row-constant fragments from the interleaved i-table (4 loads per row)
  float4 hwA[RPB], hwB[RPB], heA[RPB], heB[RPB];
#pragma unroll
  for (int r = 0; r < RPB; ++r) {
    const float* pi = itab + ((size_t)(i0 + r) * 8 + sub) * 16;
    hwA[r] = *reinterpret_cast<const float4*>(pi);
    heA[r] = *reinterpret_cast<const float4*>(pi + 4);
    hwB[r] = *reinterpret_cast<const float4*>(pi + 8);
    heB[r] = *reinterpret_cast<const float4*>(pi + 12);
  }

  const int jloc = wave * 8 + jg;        // local j at iter 0 (0..31)
  const float* pj = jtab + ((size_t)(jq * JR + jloc) * 8 + sub) * 16;

  float4 jwA = *reinterpret_cast<const float4*>(pj);
  float4 jeA = *reinterpret_cast<const float4*>(pj + 4);
  float4 jwB = *reinterpret_cast<const float4*>(pj + 8);
  float4 jeB = *reinterpret_cast<const float4*>(pj + 12);

#pragma unroll 2
  for (int it = 0; it < JR / 32; ++it) {
    const float4 cwA = jwA, ceA = jeA, cwB = jwB, ceB = jeB;
    if (it + 1 < JR / 32) {              // prefetch next j-row under compute
      pj += 32 * 128;                    // 32 j x 128 floats
      jwA = *reinterpret_cast<const float4*>(pj);
      jeA = *reinterpret_cast<const float4*>(pj + 4);
      jwB = *reinterpret_cast<const float4*>(pj + 8);
      jeB = *reinterpret_cast<const float4*>(pj + 12);
    }
    const int j = jloc + it * 32;        // local j index in [0, JR)
#pragma unroll
    for (int r = 0; r < RPB; ++r) {
      float N0, D0, N1, D1;
      quad_nd(hwA[r], heA[r], cwA, ceA, N0, D0);
      quad_nd(hwB[r], heB[r], cwB, ceB, N1, D1);
      const float rD = __builtin_amdgcn_rcpf(D0 * D1);
      float a = fmaf(N0, D1, N1 * D0) * rD;
      a = dpp_red8(a);                   // all 8 lanes hold the octet sum
      if (sub == 0) logits[r][j] = a;    // 8 lanes store 8 consecutive floats
    }
  }
  __syncthreads();

  // Fused epilogue: wave w -> row w. exp2 (max-free, log2-domain) ->
  // scalar coalesced global store (256B/wave) + register sum. No LDS回写.
  float* lrow = logits[wave];
  float* orow = out + (size_t)(i0 + wave) * KTOT + jq * JR;
  float ssum = 0.0f;
#pragma unroll
  for (int t = 0; t < 8; ++t) {
    const int k = t * 64 + lane;
    const float ev = __builtin_amdgcn_exp2f(lrow[k]);
    ssum += ev;
    orow[k] = ev;
  }
#pragma unroll
  for (int off = 32; off; off >>= 1) ssum += __shfl_xor(ssum, off);
  if (lane == 0) partials[(size_t)(i0 + wave) * 4 + jq] = ssum;
}

// ---------------------------------------------------------------------------
// Kernel C (phase 2): out[i][j] *= 1/sum(partials[i][0..3]).
// ---------------------------------------------------------------------------
__global__ __launch_bounds__(256) void norm_kernel(
    const float* __restrict__ partials, float* __restrict__ out) {
  const int idx = blockIdx.x * 256 + threadIdx.x;
#pragma unroll
  for (int t = 0; t < 4; ++t) {
    const int i4  = idx + t * (1024 * 256);      // f4 index; 512 f4 per row
    const int row = i4 >> 9;
    const float s = (partials[row * 4 + 0] + partials[row * 4 + 1]) +
                    (partials[row * 4 + 2] + partials[row * 4 + 3]);
    const float rinv = __builtin_amdgcn_rcpf(s);
    float4 v = reinterpret_cast<const float4*>(out)[i4];
    v.x *= rinv; v.y *= rinv; v.z *= rinv; v.w *= rinv;
    reinterpret_cast<float4*>(out)[i4] = v;
  }
}

// ---------------------------------------------------------------------------
extern "C" void kernel_launch(void* const* d_in, const int* in_sizes, int n_in,
                              void* d_out, int out_size, void* d_ws, size_t ws_size,
                              hipStream_t stream) {
  const float* z  = (const float*)d_in[0];
  const float* W1 = (const float*)d_in[1];
  const float* b1 = (const float*)d_in[2];
  const float* W2 = (const float*)d_in[3];
  // d_in[4] = b2: uniform logit shift, cancels in softmax.
  float* out = (float*)d_out;

  float* itab = (float*)d_ws;                     // 2048*128 f32 = 1 MB
  float* jtab = itab + (size_t)KTOT * 128;        // 1 MB
  float* partials = jtab + (size_t)KTOT * 128;    // 2048 x 4 f32

  hipLaunchKernelGGL(proj_kernel, dim3(KTOT / KPB), dim3(DDIM), 0, stream,
                     z, W1, b1, W2, itab, jtab);
  hipLaunchKernelGGL(edge_kernel, dim3((KTOT / RPB) * 4), dim3(256), 0, stream,
                     itab, jtab, out, partials);
  hipLaunchKernelGGL(norm_kernel, dim3(1024), dim3(256), 0, stream,
                     partials, out);
}